// Round 7
// baseline (157.177 us; speedup 1.0000x reference)
//
#include <hip/hip_runtime.h>
#include <hip/hip_fp16.h>
#include <math.h>

#define NH 16
#define NWL 16
#define NPOLY 5   // |γ·s| <= ~0.17  ->  deg-5 rel err ~3e-8

typedef _Float16 half8 __attribute__((ext_vector_type(8)));
typedef _Float16 half4 __attribute__((ext_vector_type(4)));
typedef _Float16 half2v __attribute__((ext_vector_type(2)));
typedef float f32x4 __attribute__((ext_vector_type(4)));

// ---------------------------------------------------------------------------
// cast x (fp32 -> f16), 8 elems/thread
// ---------------------------------------------------------------------------
__global__ __launch_bounds__(256)
void cast_x_k(const float* __restrict__ X, _Float16* __restrict__ Xh)
{
    const int i = (blockIdx.x * 256 + threadIdx.x) * 8;
    float4 v0 = *(const float4*)&X[i];
    float4 v1 = *(const float4*)&X[i + 4];
    half8 o;
    o[0] = (_Float16)v0.x; o[1] = (_Float16)v0.y; o[2] = (_Float16)v0.z; o[3] = (_Float16)v0.w;
    o[4] = (_Float16)v1.x; o[5] = (_Float16)v1.y; o[6] = (_Float16)v1.z; o[7] = (_Float16)v1.w;
    *(half8*)&Xh[i] = o;
}

// ---------------------------------------------------------------------------
// cast + transpose W[e][f] -> WT[f][e] f16, 64x64 tiles, z picks which W
// ---------------------------------------------------------------------------
__global__ __launch_bounds__(256)
void castT_w(const float* __restrict__ W0, const float* __restrict__ W1,
             const float* __restrict__ W2, const float* __restrict__ W3,
             _Float16* __restrict__ WT)
{
    const float* W = W0;
    if (blockIdx.z == 1) W = W1;
    if (blockIdx.z == 2) W = W2;
    if (blockIdx.z == 3) W = W3;
    _Float16* out = WT + ((size_t)blockIdx.z << 20);

    __shared__ float Ts[64][65];
    const int t = threadIdx.x;
    const int ebase = blockIdx.y * 64;
    const int fbase = blockIdx.x * 64;

    {
        const int r0 = (t >> 4) * 4;
        const int c0 = (t & 15) * 4;
#pragma unroll
        for (int r = 0; r < 4; ++r) {
            float4 v = *(const float4*)&W[(size_t)(ebase + r0 + r) * 1024 + fbase + c0];
            Ts[r0 + r][c0 + 0] = v.x;
            Ts[r0 + r][c0 + 1] = v.y;
            Ts[r0 + r][c0 + 2] = v.z;
            Ts[r0 + r][c0 + 3] = v.w;
        }
    }
    __syncthreads();

    const int f = t >> 2;
    const int eseg = (t & 3) * 16;
    half8 lo, hi;
#pragma unroll
    for (int j = 0; j < 8; ++j) lo[j] = (_Float16)Ts[eseg + j][f];
#pragma unroll
    for (int j = 0; j < 8; ++j) hi[j] = (_Float16)Ts[eseg + 8 + j][f];
    *(half8*)&out[(size_t)(fbase + f) * 1024 + ebase + eseg]     = lo;
    *(half8*)&out[(size_t)(fbase + f) * 1024 + ebase + eseg + 8] = hi;
}

// ---------------------------------------------------------------------------
// MFMA GEMM (f16): C[s][f] = sum_e A[s][e]*W[e][f] + bias[f]
// 64x64 tile, BK=32, 4 waves (2x2), 16x16x32_f16 frags, double-buffered LDS.
// MODE 0: fp32 out[s][f]
// MODE 1: f16 head-split: z=0,1 -> O[h][s][d]; z=2 -> transposed O[h][d][s]
// ---------------------------------------------------------------------------
template<int MODE>
__global__ __launch_bounds__(256)
void gemm_mfma(const _Float16* __restrict__ A,
               const _Float16* __restrict__ BtBase,
               const float* __restrict__ B0, const float* __restrict__ B1,
               const float* __restrict__ B2,
               void* __restrict__ O0p, void* __restrict__ O1p, void* __restrict__ O2p)
{
    const int z = blockIdx.z;
    const _Float16* Bt = BtBase + ((size_t)z << 20);
    const float* bias = B0; void* Op = O0p;
    if (z == 1) { bias = B1; Op = O1p; }
    if (z == 2) { bias = B2; Op = O2p; }

    __shared__ _Float16 As[2][64][40];
    __shared__ _Float16 Bs[2][64][40];

    const int t = threadIdx.x;
    const int lane = t & 63;
    const int w = t >> 6;
    const int w_r = w >> 1;
    const int w_c = w & 1;
    const int sbase = blockIdx.y * 64;
    const int fbase = blockIdx.x * 64;

    const int srow = t >> 2;
    const int skseg = (t & 3) * 8;

    f32x4 acc[2][2];
#pragma unroll
    for (int m = 0; m < 2; ++m)
#pragma unroll
        for (int n = 0; n < 2; ++n) acc[m][n] = (f32x4){0.f, 0.f, 0.f, 0.f};

    const int lr = lane & 15;
    const int lk = (lane >> 4) * 8;

    {
        *(half8*)&As[0][srow][skseg] = *(const half8*)&A [(size_t)(sbase + srow) * 1024 + skseg];
        *(half8*)&Bs[0][srow][skseg] = *(const half8*)&Bt[(size_t)(fbase + srow) * 1024 + skseg];
    }
    __syncthreads();

    for (int tile = 0; tile < 32; ++tile) {
        const int cur = tile & 1;
        if (tile < 31) {
            const int kb = (tile + 1) * 32;
            half8 av = *(const half8*)&A [(size_t)(sbase + srow) * 1024 + kb + skseg];
            half8 bv = *(const half8*)&Bt[(size_t)(fbase + srow) * 1024 + kb + skseg];
            *(half8*)&As[cur ^ 1][srow][skseg] = av;
            *(half8*)&Bs[cur ^ 1][srow][skseg] = bv;
        }
        half8 a0 = *(const half8*)&As[cur][w_r * 32 + 0  + lr][lk];
        half8 a1 = *(const half8*)&As[cur][w_r * 32 + 16 + lr][lk];
        half8 b0 = *(const half8*)&Bs[cur][w_c * 32 + 0  + lr][lk];
        half8 b1 = *(const half8*)&Bs[cur][w_c * 32 + 16 + lr][lk];
        acc[0][0] = __builtin_amdgcn_mfma_f32_16x16x32_f16(a0, b0, acc[0][0], 0, 0, 0);
        acc[0][1] = __builtin_amdgcn_mfma_f32_16x16x32_f16(a0, b1, acc[0][1], 0, 0, 0);
        acc[1][0] = __builtin_amdgcn_mfma_f32_16x16x32_f16(a1, b0, acc[1][0], 0, 0, 0);
        acc[1][1] = __builtin_amdgcn_mfma_f32_16x16x32_f16(a1, b1, acc[1][1], 0, 0, 0);
        __syncthreads();
    }

#pragma unroll
    for (int m = 0; m < 2; ++m) {
        const int row0 = sbase + w_r * 32 + m * 16 + (lane >> 4) * 4;
#pragma unroll
        for (int n = 0; n < 2; ++n) {
            const int col = fbase + w_c * 32 + n * 16 + (lane & 15);
            const float bval = bias[col];
            if (MODE == 0) {
                float* O = (float*)Op;
#pragma unroll
                for (int r = 0; r < 4; ++r)
                    O[(size_t)(row0 + r) * 1024 + col] = acc[m][n][r] + bval;
            } else {
                _Float16* O = (_Float16*)Op;
                const int hh = col >> 6;
                const int d = col & 63;
                if (z == 2) {   // V transposed: O[h][d][s]
                    half4 o;
#pragma unroll
                    for (int r = 0; r < 4; ++r) o[r] = (_Float16)(acc[m][n][r] + bval);
                    *(half4*)&O[((size_t)hh << 16) + (size_t)d * 1024 + row0] = o;
                } else {        // Q/K: O[h][s][d]
#pragma unroll
                    for (int r = 0; r < 4; ++r)
                        O[((size_t)hh << 16) + (size_t)(row0 + r) * 64 + d] =
                            (_Float16)(acc[m][n][r] + bval);
                }
            }
        }
    }
}

// ---------------------------------------------------------------------------
// Fused attention, moment/poly form.
// 256 threads = 4 waves; block = (head, 8 q rows); wave w owns k-range
// [w*256, w*256+256), barrier-free in the k-loop. Grid 2048 blocks =
// 8 blocks/CU x 4 waves = 32 waves/CU (100% ceiling) with ~18KB LDS and
// VGPR kept under the 64-reg / 8-wave cliff (R6 lesson: forcing occupancy
// via launch_bounds(512,8) capped VGPR at 32 -> scratch spill, FETCH x20).
// Lanes lr>=8 duplicate q rows (lr&7); MFMA row-independence makes the
// duplicates harmless, writes are guarded.
// Phase A: channel-independent moments M_n = sum_k s^n 2^{abar s} (n<=5);
// den_i = sum_n (g_i^n/n!) M_n. Phase B: P(s) = 2^{abar s} * Horner(s;c),
// c_n = sum_i wgt_i g_i^n/n!.  XCD swizzle: 2 heads/XCD -> K/V L2-resident.
// ---------------------------------------------------------------------------
__global__ __launch_bounds__(256, 8)
void attn_k(const _Float16* __restrict__ Qg, const _Float16* __restrict__ Kg,
            const _Float16* __restrict__ Vg, const float* __restrict__ pm,
            const float* __restrict__ iwp, _Float16* __restrict__ comb)
{
    const int wg  = blockIdx.x;
    const int xcd = wg & 7;
    const int idx = wg >> 3;            // 0..255
    const int h   = xcd * 2 + (idx >> 7);
    const int qt  = idx & 127;          // 8-row q tile

    const int t = threadIdx.x;
    const int lane = t & 63;
    const int w = t >> 6;               // wave id = k-quarter
    const int lr = lane & 15;
    const int lg = lane >> 4;

    __shared__ _Float16 Ps[4][16][68];      // per-wave P chunk [qcol][k64]
    __shared__ union {
        float Mom[4][16][NPOLY + 1];        // per-wave moment partials
        float Red[4][8][68];                // O-partial reduce (after barrier)
    } U;
    __shared__ float sa[16], siw[16];
    __shared__ float gt[16][NPOLY + 1];     // g_i^n / n!

    if (t < 16) {
        float m = cosf(pm[t * NH + h]);
        sa[t] = m * m * 0.125f * 1.44269504f;   // a_i (log2 scale)
        siw[t] = iwp[t];
    }
    __syncthreads();

    float amin = sa[0], amax = sa[0];
#pragma unroll
    for (int i = 1; i < NWL; ++i) {
        amin = fminf(amin, sa[i]);
        amax = fmaxf(amax, sa[i]);
    }
    const float abar = 0.5f * (amin + amax);

    if (t < 16) {
        float g = (sa[t] - abar) * 0.69314718f;  // natural-log residual
        float p = 1.f;
        gt[t][0] = 1.f;
#pragma unroll
        for (int n = 1; n <= NPOLY; ++n) {
            p *= g / (float)n;
            gt[t][n] = p;
        }
    }

    // Q fragment (B-operand): col = q-local = lr&7 (dup for lr>=8), k-seg lg*8
    const _Float16* Qrow = Qg + ((size_t)h << 16) + (size_t)(qt * 8 + (lr & 7)) * 64;
    half8 q0 = *(const half8*)&Qrow[lg * 8];
    half8 q1 = *(const half8*)&Qrow[32 + lg * 8];

    const _Float16* Kq = Kg + ((size_t)h << 16) + (size_t)(w * 256) * 64;  // wave's k-quarter
    const _Float16* Vh = Vg + ((size_t)h << 16);                           // V^T [d][s]

    // ---- Phase A: moments over this wave's 256 k ----
    float M[NPOLY + 1];
#pragma unroll
    for (int n = 0; n <= NPOLY; ++n) M[n] = 0.f;

    for (int ch = 0; ch < 4; ++ch) {
#pragma unroll
        for (int kf = 0; kf < 4; ++kf) {
            const _Float16* Kr = Kq + (size_t)(ch * 64 + kf * 16 + lr) * 64;
            half8 a0 = *(const half8*)&Kr[lg * 8];
            half8 a1 = *(const half8*)&Kr[32 + lg * 8];
            f32x4 s2 = (f32x4){0.f, 0.f, 0.f, 0.f};
            s2 = __builtin_amdgcn_mfma_f32_16x16x32_f16(a0, q0, s2, 0, 0, 0);
            s2 = __builtin_amdgcn_mfma_f32_16x16x32_f16(a1, q1, s2, 0, 0, 0);
#pragma unroll
            for (int r = 0; r < 4; ++r) {
                const float sv = s2[r];
                float e = exp2f(abar * sv);
                M[0] += e;
#pragma unroll
                for (int n = 1; n <= NPOLY; ++n) {
                    e *= sv;
                    M[n] += e;
                }
            }
        }
    }

    // sum over the 4 lane-groups (k bits) -> per-q partial for this wave
#pragma unroll
    for (int off = 16; off < 64; off <<= 1)
#pragma unroll
        for (int n = 0; n <= NPOLY; ++n)
            M[n] += __shfl_xor(M[n], off);

    if (lg == 0) {
#pragma unroll
        for (int n = 0; n <= NPOLY; ++n) U.Mom[w][lr][n] = M[n];
    }
    __syncthreads();

    // full-k moments for q = lr (dup rows for lr>=8 stay consistent)
#pragma unroll
    for (int n = 0; n <= NPOLY; ++n)
        M[n] = U.Mom[0][lr][n] + U.Mom[1][lr][n] + U.Mom[2][lr][n] + U.Mom[3][lr][n];

    // den_i = sum_n gt[i][n]*M[n]; wgt_i = iw_i/(16 den_i); c_n = sum_i wgt_i gt[i][n]
    float c[NPOLY + 1];
#pragma unroll
    for (int n = 0; n <= NPOLY; ++n) c[n] = 0.f;
#pragma unroll
    for (int i = 0; i < NWL; ++i) {
        float den = 0.f;
#pragma unroll
        for (int n = 0; n <= NPOLY; ++n) den = fmaf(gt[i][n], M[n], den);
        const float wgt = siw[i] / (den * 16.0f);
#pragma unroll
        for (int n = 0; n <= NPOLY; ++n) c[n] = fmaf(wgt, gt[i][n], c[n]);
    }
    __syncthreads();   // all Mom reads done; U reused as Red below

    // ---- Phase B: P chunks + PV partials over this wave's 256 k ----
    f32x4 oacc[4];
#pragma unroll
    for (int n = 0; n < 4; ++n) oacc[n] = (f32x4){0.f, 0.f, 0.f, 0.f};

    for (int ch = 0; ch < 4; ++ch) {
#pragma unroll
        for (int kf = 0; kf < 4; ++kf) {
            const _Float16* Kr = Kq + (size_t)(ch * 64 + kf * 16 + lr) * 64;
            half8 a0 = *(const half8*)&Kr[lg * 8];
            half8 a1 = *(const half8*)&Kr[32 + lg * 8];
            f32x4 s2 = (f32x4){0.f, 0.f, 0.f, 0.f};
            s2 = __builtin_amdgcn_mfma_f32_16x16x32_f16(a0, q0, s2, 0, 0, 0);
            s2 = __builtin_amdgcn_mfma_f32_16x16x32_f16(a1, q1, s2, 0, 0, 0);
            half4 ph;
#pragma unroll
            for (int r = 0; r < 4; ++r) {
                const float sv = s2[r];
                const float e = exp2f(abar * sv);
                float poly = c[NPOLY];
#pragma unroll
                for (int n = NPOLY - 1; n >= 0; --n)
                    poly = fmaf(poly, sv, c[n]);
                ph[r] = (_Float16)(e * poly);
            }
            // P[qcol=lr][k-local = kf*16 + lg*4 + r], per-wave private buffer
            *(half4*)&Ps[w][lr][kf * 16 + lg * 4] = ph;
        }
        // same-wave LDS dep; compiler inserts lgkm waits
        half8 pa0 = *(const half8*)&Ps[w][lr][lg * 8];
        half8 pa1 = *(const half8*)&Ps[w][lr][32 + lg * 8];
        const int kcol = w * 256 + ch * 64;
#pragma unroll
        for (int n = 0; n < 4; ++n) {
            const _Float16* Vr = Vh + (size_t)(n * 16 + lr) * 1024 + kcol;
            half8 vb0 = *(const half8*)&Vr[lg * 8];
            half8 vb1 = *(const half8*)&Vr[32 + lg * 8];
            oacc[n] = __builtin_amdgcn_mfma_f32_16x16x32_f16(pa0, vb0, oacc[n], 0, 0, 0);
            oacc[n] = __builtin_amdgcn_mfma_f32_16x16x32_f16(pa1, vb1, oacc[n], 0, 0, 0);
        }
    }

    // ---- O-partial reduce: valid q rows are lg*4+r < 8 (lg<2) ----
    if (lg < 2) {
#pragma unroll
        for (int n = 0; n < 4; ++n)
#pragma unroll
            for (int r = 0; r < 4; ++r)
                U.Red[w][lg * 4 + r][n * 16 + lr] = oacc[n][r];
    }
    __syncthreads();

    // final: 256 threads -> q = t>>5 (0..7), d0 = (t&31)*2 (2 outputs each)
    {
        const int q = t >> 5;
        const int d0 = (t & 31) * 2;
        float s0 = U.Red[0][q][d0] + U.Red[1][q][d0] + U.Red[2][q][d0] + U.Red[3][q][d0];
        float s1 = U.Red[0][q][d0 + 1] + U.Red[1][q][d0 + 1]
                 + U.Red[2][q][d0 + 1] + U.Red[3][q][d0 + 1];
        half2v o;
        o[0] = (_Float16)s0;
        o[1] = (_Float16)s1;
        *(half2v*)&comb[(size_t)(qt * 8 + q) * 1024 + h * 64 + d0] = o;
    }
}

// ---------------------------------------------------------------------------
extern "C" void kernel_launch(void* const* d_in, const int* in_sizes, int n_in,
                              void* d_out, int out_size, void* d_ws, size_t ws_size,
                              hipStream_t stream)
{
    const float* x  = (const float*)d_in[0];
    const float* Wq = (const float*)d_in[1];
    const float* bq = (const float*)d_in[2];
    const float* Wk = (const float*)d_in[3];
    const float* bk = (const float*)d_in[4];
    const float* Wv = (const float*)d_in[5];
    const float* bv = (const float*)d_in[6];
    const float* Wo = (const float*)d_in[7];
    const float* bo = (const float*)d_in[8];
    const float* pm = (const float*)d_in[9];
    const float* iw = (const float*)d_in[10];
    float* out = (float*)d_out;

    // ws (f16 elems): Xh 1M (reused as comb) | WT 4M | Q 1M | K 1M | Vt 1M = 16 MB
    _Float16* Xh = (_Float16*)d_ws;
    _Float16* WT = Xh + (1u << 20);
    _Float16* Qh = WT + (4u << 20);
    _Float16* Kh = Qh + (1u << 20);
    _Float16* Vt = Kh + (1u << 20);
    _Float16* comb = Xh;   // Xh dead after QKV GEMM

    dim3 blk(256);
    cast_x_k<<<dim3(512), blk, 0, stream>>>(x, Xh);
    castT_w<<<dim3(16, 16, 4), blk, 0, stream>>>(Wq, Wk, Wv, Wo, WT);
    gemm_mfma<1><<<dim3(16, 16, 3), blk, 0, stream>>>(Xh, WT, bq, bk, bv, Qh, Kh, Vt);
    attn_k<<<dim3(2048), blk, 0, stream>>>(Qh, Kh, Vt, pm, iw, comb);
    gemm_mfma<0><<<dim3(16, 16, 1), blk, 0, stream>>>(
        comb, WT + (3u << 20), bo, bo, bo, out, out, out);
}

// Round 8
// 101.718 us; speedup vs baseline: 1.5452x; 1.5452x over previous
//
#include <hip/hip_runtime.h>
#include <hip/hip_fp16.h>
#include <math.h>

#define NH 16
#define NWL 16
#define NPOLY 5   // |γ·s| <= ~0.17  ->  deg-5 rel err ~3e-8

typedef _Float16 half8 __attribute__((ext_vector_type(8)));
typedef _Float16 half4 __attribute__((ext_vector_type(4)));
typedef _Float16 half2v __attribute__((ext_vector_type(2)));
typedef float f32x4 __attribute__((ext_vector_type(4)));

// ---------------------------------------------------------------------------
// cast x (fp32 -> f16), 8 elems/thread
// ---------------------------------------------------------------------------
__global__ __launch_bounds__(256)
void cast_x_k(const float* __restrict__ X, _Float16* __restrict__ Xh)
{
    const int i = (blockIdx.x * 256 + threadIdx.x) * 8;
    float4 v0 = *(const float4*)&X[i];
    float4 v1 = *(const float4*)&X[i + 4];
    half8 o;
    o[0] = (_Float16)v0.x; o[1] = (_Float16)v0.y; o[2] = (_Float16)v0.z; o[3] = (_Float16)v0.w;
    o[4] = (_Float16)v1.x; o[5] = (_Float16)v1.y; o[6] = (_Float16)v1.z; o[7] = (_Float16)v1.w;
    *(half8*)&Xh[i] = o;
}

// ---------------------------------------------------------------------------
// cast + transpose W[e][f] -> WT[f][e] f16, 64x64 tiles, z picks which W
// ---------------------------------------------------------------------------
__global__ __launch_bounds__(256)
void castT_w(const float* __restrict__ W0, const float* __restrict__ W1,
             const float* __restrict__ W2, const float* __restrict__ W3,
             _Float16* __restrict__ WT)
{
    const float* W = W0;
    if (blockIdx.z == 1) W = W1;
    if (blockIdx.z == 2) W = W2;
    if (blockIdx.z == 3) W = W3;
    _Float16* out = WT + ((size_t)blockIdx.z << 20);

    __shared__ float Ts[64][65];
    const int t = threadIdx.x;
    const int ebase = blockIdx.y * 64;
    const int fbase = blockIdx.x * 64;

    {
        const int r0 = (t >> 4) * 4;
        const int c0 = (t & 15) * 4;
#pragma unroll
        for (int r = 0; r < 4; ++r) {
            float4 v = *(const float4*)&W[(size_t)(ebase + r0 + r) * 1024 + fbase + c0];
            Ts[r0 + r][c0 + 0] = v.x;
            Ts[r0 + r][c0 + 1] = v.y;
            Ts[r0 + r][c0 + 2] = v.z;
            Ts[r0 + r][c0 + 3] = v.w;
        }
    }
    __syncthreads();

    const int f = t >> 2;
    const int eseg = (t & 3) * 16;
    half8 lo, hi;
#pragma unroll
    for (int j = 0; j < 8; ++j) lo[j] = (_Float16)Ts[eseg + j][f];
#pragma unroll
    for (int j = 0; j < 8; ++j) hi[j] = (_Float16)Ts[eseg + 8 + j][f];
    *(half8*)&out[(size_t)(fbase + f) * 1024 + ebase + eseg]     = lo;
    *(half8*)&out[(size_t)(fbase + f) * 1024 + ebase + eseg + 8] = hi;
}

// ---------------------------------------------------------------------------
// MFMA GEMM (f16): C[s][f] = sum_e A[s][e]*W[e][f] + bias[f]
// 64x64 tile, BK=32, 4 waves (2x2), 16x16x32_f16 frags, double-buffered LDS.
// MODE 0: fp32 out[s][f]
// MODE 1: f16 head-split: z=0,1 -> O[h][s][d]; z=2 -> transposed O[h][d][s]
// ---------------------------------------------------------------------------
template<int MODE>
__global__ __launch_bounds__(256)
void gemm_mfma(const _Float16* __restrict__ A,
               const _Float16* __restrict__ BtBase,
               const float* __restrict__ B0, const float* __restrict__ B1,
               const float* __restrict__ B2,
               void* __restrict__ O0p, void* __restrict__ O1p, void* __restrict__ O2p)
{
    const int z = blockIdx.z;
    const _Float16* Bt = BtBase + ((size_t)z << 20);
    const float* bias = B0; void* Op = O0p;
    if (z == 1) { bias = B1; Op = O1p; }
    if (z == 2) { bias = B2; Op = O2p; }

    __shared__ _Float16 As[2][64][40];
    __shared__ _Float16 Bs[2][64][40];

    const int t = threadIdx.x;
    const int lane = t & 63;
    const int w = t >> 6;
    const int w_r = w >> 1;
    const int w_c = w & 1;
    const int sbase = blockIdx.y * 64;
    const int fbase = blockIdx.x * 64;

    const int srow = t >> 2;
    const int skseg = (t & 3) * 8;

    f32x4 acc[2][2];
#pragma unroll
    for (int m = 0; m < 2; ++m)
#pragma unroll
        for (int n = 0; n < 2; ++n) acc[m][n] = (f32x4){0.f, 0.f, 0.f, 0.f};

    const int lr = lane & 15;
    const int lk = (lane >> 4) * 8;

    {
        *(half8*)&As[0][srow][skseg] = *(const half8*)&A [(size_t)(sbase + srow) * 1024 + skseg];
        *(half8*)&Bs[0][srow][skseg] = *(const half8*)&Bt[(size_t)(fbase + srow) * 1024 + skseg];
    }
    __syncthreads();

    for (int tile = 0; tile < 32; ++tile) {
        const int cur = tile & 1;
        if (tile < 31) {
            const int kb = (tile + 1) * 32;
            half8 av = *(const half8*)&A [(size_t)(sbase + srow) * 1024 + kb + skseg];
            half8 bv = *(const half8*)&Bt[(size_t)(fbase + srow) * 1024 + kb + skseg];
            *(half8*)&As[cur ^ 1][srow][skseg] = av;
            *(half8*)&Bs[cur ^ 1][srow][skseg] = bv;
        }
        half8 a0 = *(const half8*)&As[cur][w_r * 32 + 0  + lr][lk];
        half8 a1 = *(const half8*)&As[cur][w_r * 32 + 16 + lr][lk];
        half8 b0 = *(const half8*)&Bs[cur][w_c * 32 + 0  + lr][lk];
        half8 b1 = *(const half8*)&Bs[cur][w_c * 32 + 16 + lr][lk];
        acc[0][0] = __builtin_amdgcn_mfma_f32_16x16x32_f16(a0, b0, acc[0][0], 0, 0, 0);
        acc[0][1] = __builtin_amdgcn_mfma_f32_16x16x32_f16(a0, b1, acc[0][1], 0, 0, 0);
        acc[1][0] = __builtin_amdgcn_mfma_f32_16x16x32_f16(a1, b0, acc[1][0], 0, 0, 0);
        acc[1][1] = __builtin_amdgcn_mfma_f32_16x16x32_f16(a1, b1, acc[1][1], 0, 0, 0);
        __syncthreads();
    }

#pragma unroll
    for (int m = 0; m < 2; ++m) {
        const int row0 = sbase + w_r * 32 + m * 16 + (lane >> 4) * 4;
#pragma unroll
        for (int n = 0; n < 2; ++n) {
            const int col = fbase + w_c * 32 + n * 16 + (lane & 15);
            const float bval = bias[col];
            if (MODE == 0) {
                float* O = (float*)Op;
#pragma unroll
                for (int r = 0; r < 4; ++r)
                    O[(size_t)(row0 + r) * 1024 + col] = acc[m][n][r] + bval;
            } else {
                _Float16* O = (_Float16*)Op;
                const int hh = col >> 6;
                const int d = col & 63;
                if (z == 2) {   // V transposed: O[h][d][s]
                    half4 o;
#pragma unroll
                    for (int r = 0; r < 4; ++r) o[r] = (_Float16)(acc[m][n][r] + bval);
                    *(half4*)&O[((size_t)hh << 16) + (size_t)d * 1024 + row0] = o;
                } else {        // Q/K: O[h][s][d]
#pragma unroll
                    for (int r = 0; r < 4; ++r)
                        O[((size_t)hh << 16) + (size_t)(row0 + r) * 64 + d] =
                            (_Float16)(acc[m][n][r] + bval);
                }
            }
        }
    }
}

// ---------------------------------------------------------------------------
// Fused attention, moment/poly form.
// 512 threads = 8 waves; block = (head, 16 REAL q rows — no duplicate lanes);
// wave w owns k-range [w*128, w*128+128), barrier-free in the k-loop.
// Grid 1024 blocks; LDS ~35KB (Mom/Red union) -> 4 blocks/CU x 8 waves =
// 32 waves/CU ceiling. launch_bounds(512,4): 128-reg cap so the ~50-reg
// live set + MFMA AGPRs fit WITHOUT spill (R6/R7 lesson: forcing 8 waves/EU
// splits the unified 64-reg cap ~32 arch + 32 acc -> scratch spill, 9-20x
// FETCH inflation).
// Phase A: channel-independent moments M_n = sum_k s^n 2^{abar s} (n<=5);
// den_i = sum_n (g_i^n/n!) M_n. Phase B: P(s) = 2^{abar s} * Horner(s;c),
// c_n = sum_i wgt_i g_i^n/n!.  XCD swizzle: 2 heads/XCD -> K/V L2-resident.
// ---------------------------------------------------------------------------
__global__ __launch_bounds__(512, 4)
void attn_k(const _Float16* __restrict__ Qg, const _Float16* __restrict__ Kg,
            const _Float16* __restrict__ Vg, const float* __restrict__ pm,
            const float* __restrict__ iwp, _Float16* __restrict__ comb)
{
    const int wg  = blockIdx.x;
    const int xcd = wg & 7;
    const int idx = wg >> 3;            // 0..127
    const int h   = xcd * 2 + (idx >> 6);
    const int qt  = idx & 63;           // 16-row q tile

    const int t = threadIdx.x;
    const int lane = t & 63;
    const int w = t >> 6;               // wave id = k-eighth
    const int lr = lane & 15;
    const int lg = lane >> 4;

    __shared__ _Float16 Ps[8][16][68];      // per-wave P chunk [qcol][k64]
    __shared__ union {
        float Mom[8][16][NPOLY + 1];        // per-wave moment partials
        float Red[4][16][68];               // O-partial 2-stage reduce
    } U;
    __shared__ float sa[16], siw[16];
    __shared__ float gt[16][NPOLY + 1];     // g_i^n / n!

    if (t < 16) {
        float m = cosf(pm[t * NH + h]);
        sa[t] = m * m * 0.125f * 1.44269504f;   // a_i (log2 scale)
        siw[t] = iwp[t];
    }
    __syncthreads();

    float amin = sa[0], amax = sa[0];
#pragma unroll
    for (int i = 1; i < NWL; ++i) {
        amin = fminf(amin, sa[i]);
        amax = fmaxf(amax, sa[i]);
    }
    const float abar = 0.5f * (amin + amax);

    if (t < 16) {
        float g = (sa[t] - abar) * 0.69314718f;  // natural-log residual
        float p = 1.f;
        gt[t][0] = 1.f;
#pragma unroll
        for (int n = 1; n <= NPOLY; ++n) {
            p *= g / (float)n;
            gt[t][n] = p;
        }
    }

    // Q fragments (B-operand): col = q-local = lr, k-seg = lg*8 (all waves same)
    const _Float16* Qrow = Qg + ((size_t)h << 16) + (size_t)(qt * 16 + lr) * 64;
    half8 q0 = *(const half8*)&Qrow[lg * 8];
    half8 q1 = *(const half8*)&Qrow[32 + lg * 8];

    const _Float16* Kq = Kg + ((size_t)h << 16) + (size_t)(w * 128) * 64;  // wave's k-eighth
    const _Float16* Vh = Vg + ((size_t)h << 16);                           // V^T [d][s]

    // ---- Phase A: moments over this wave's 128 k ----
    float M[NPOLY + 1];
#pragma unroll
    for (int n = 0; n <= NPOLY; ++n) M[n] = 0.f;

#pragma unroll
    for (int kf = 0; kf < 8; ++kf) {
        const _Float16* Kr = Kq + (size_t)(kf * 16 + lr) * 64;
        half8 a0 = *(const half8*)&Kr[lg * 8];
        half8 a1 = *(const half8*)&Kr[32 + lg * 8];
        f32x4 s2 = (f32x4){0.f, 0.f, 0.f, 0.f};
        s2 = __builtin_amdgcn_mfma_f32_16x16x32_f16(a0, q0, s2, 0, 0, 0);
        s2 = __builtin_amdgcn_mfma_f32_16x16x32_f16(a1, q1, s2, 0, 0, 0);
#pragma unroll
        for (int r = 0; r < 4; ++r) {
            const float sv = s2[r];
            float e = exp2f(abar * sv);
            M[0] += e;
#pragma unroll
            for (int n = 1; n <= NPOLY; ++n) {
                e *= sv;
                M[n] += e;
            }
        }
    }

    // sum over the 4 lane-groups (k bits) -> per-q partial for this wave
#pragma unroll
    for (int off = 16; off < 64; off <<= 1)
#pragma unroll
        for (int n = 0; n <= NPOLY; ++n)
            M[n] += __shfl_xor(M[n], off);

    if (lg == 0) {
#pragma unroll
        for (int n = 0; n <= NPOLY; ++n) U.Mom[w][lr][n] = M[n];
    }
    __syncthreads();

    // full-k moments per q-row = lr (broadcast reads across lg)
#pragma unroll
    for (int n = 0; n <= NPOLY; ++n) {
        float s = 0.f;
#pragma unroll
        for (int ww = 0; ww < 8; ++ww) s += U.Mom[ww][lr][n];
        M[n] = s;
    }

    // den_i = sum_n gt[i][n]*M[n]; wgt_i = iw_i/(16 den_i); c_n = sum_i wgt_i gt[i][n]
    float c[NPOLY + 1];
#pragma unroll
    for (int n = 0; n <= NPOLY; ++n) c[n] = 0.f;
#pragma unroll
    for (int i = 0; i < NWL; ++i) {
        float den = 0.f;
#pragma unroll
        for (int n = 0; n <= NPOLY; ++n) den = fmaf(gt[i][n], M[n], den);
        const float wgt = siw[i] / (den * 16.0f);
#pragma unroll
        for (int n = 0; n <= NPOLY; ++n) c[n] = fmaf(wgt, gt[i][n], c[n]);
    }
    __syncthreads();   // all Mom reads done; U reused as Red below

    // ---- Phase B: P chunks + PV partials over this wave's 128 k ----
    f32x4 oacc[4];
#pragma unroll
    for (int n = 0; n < 4; ++n) oacc[n] = (f32x4){0.f, 0.f, 0.f, 0.f};

#pragma unroll
    for (int ch = 0; ch < 2; ++ch) {
#pragma unroll
        for (int kf = 0; kf < 4; ++kf) {
            const _Float16* Kr = Kq + (size_t)(ch * 64 + kf * 16 + lr) * 64;
            half8 a0 = *(const half8*)&Kr[lg * 8];
            half8 a1 = *(const half8*)&Kr[32 + lg * 8];
            f32x4 s2 = (f32x4){0.f, 0.f, 0.f, 0.f};
            s2 = __builtin_amdgcn_mfma_f32_16x16x32_f16(a0, q0, s2, 0, 0, 0);
            s2 = __builtin_amdgcn_mfma_f32_16x16x32_f16(a1, q1, s2, 0, 0, 0);
            half4 ph;
#pragma unroll
            for (int r = 0; r < 4; ++r) {
                const float sv = s2[r];
                const float e = exp2f(abar * sv);
                float poly = c[NPOLY];
#pragma unroll
                for (int n = NPOLY - 1; n >= 0; --n)
                    poly = fmaf(poly, sv, c[n]);
                ph[r] = (_Float16)(e * poly);
            }
            // P[qcol=lr][k-local = kf*16 + lg*4 + r], per-wave private buffer
            *(half4*)&Ps[w][lr][kf * 16 + lg * 4] = ph;
        }
        // same-wave LDS dep; compiler inserts lgkm waits
        half8 pa0 = *(const half8*)&Ps[w][lr][lg * 8];
        half8 pa1 = *(const half8*)&Ps[w][lr][32 + lg * 8];
        const int kcol = w * 128 + ch * 64;
#pragma unroll
        for (int n = 0; n < 4; ++n) {
            const _Float16* Vr = Vh + (size_t)(n * 16 + lr) * 1024 + kcol;
            half8 vb0 = *(const half8*)&Vr[lg * 8];
            half8 vb1 = *(const half8*)&Vr[32 + lg * 8];
            oacc[n] = __builtin_amdgcn_mfma_f32_16x16x32_f16(pa0, vb0, oacc[n], 0, 0, 0);
            oacc[n] = __builtin_amdgcn_mfma_f32_16x16x32_f16(pa1, vb1, oacc[n], 0, 0, 0);
        }
    }

    // ---- O-partial 2-stage reduce ----
    // stage 1: waves 4..7 write their partials
    if (w >= 4) {
#pragma unroll
        for (int n = 0; n < 4; ++n)
#pragma unroll
            for (int r = 0; r < 4; ++r)
                U.Red[w - 4][lg * 4 + r][n * 16 + lr] = oacc[n][r];
    }
    __syncthreads();
    // stage 2: waves 0..3 add theirs on top
    if (w < 4) {
#pragma unroll
        for (int n = 0; n < 4; ++n)
#pragma unroll
            for (int r = 0; r < 4; ++r)
                U.Red[w][lg * 4 + r][n * 16 + lr] += oacc[n][r];
    }
    __syncthreads();

    // final: 512 threads -> q = t>>5, d0 = (t&31)*2 (2 outputs each)
    {
        const int q = t >> 5;
        const int d0 = (t & 31) * 2;
        float s0 = U.Red[0][q][d0] + U.Red[1][q][d0] + U.Red[2][q][d0] + U.Red[3][q][d0];
        float s1 = U.Red[0][q][d0 + 1] + U.Red[1][q][d0 + 1]
                 + U.Red[2][q][d0 + 1] + U.Red[3][q][d0 + 1];
        half2v o;
        o[0] = (_Float16)s0;
        o[1] = (_Float16)s1;
        *(half2v*)&comb[(size_t)(qt * 16 + q) * 1024 + h * 64 + d0] = o;
    }
}

// ---------------------------------------------------------------------------
extern "C" void kernel_launch(void* const* d_in, const int* in_sizes, int n_in,
                              void* d_out, int out_size, void* d_ws, size_t ws_size,
                              hipStream_t stream)
{
    const float* x  = (const float*)d_in[0];
    const float* Wq = (const float*)d_in[1];
    const float* bq = (const float*)d_in[2];
    const float* Wk = (const float*)d_in[3];
    const float* bk = (const float*)d_in[4];
    const float* Wv = (const float*)d_in[5];
    const float* bv = (const float*)d_in[6];
    const float* Wo = (const float*)d_in[7];
    const float* bo = (const float*)d_in[8];
    const float* pm = (const float*)d_in[9];
    const float* iw = (const float*)d_in[10];
    float* out = (float*)d_out;

    // ws (f16 elems): Xh 1M (reused as comb) | WT 4M | Q 1M | K 1M | Vt 1M = 16 MB
    _Float16* Xh = (_Float16*)d_ws;
    _Float16* WT = Xh + (1u << 20);
    _Float16* Qh = WT + (4u << 20);
    _Float16* Kh = Qh + (1u << 20);
    _Float16* Vt = Kh + (1u << 20);
    _Float16* comb = Xh;   // Xh dead after QKV GEMM

    dim3 blk(256);
    cast_x_k<<<dim3(512), blk, 0, stream>>>(x, Xh);
    castT_w<<<dim3(16, 16, 4), blk, 0, stream>>>(Wq, Wk, Wv, Wo, WT);
    gemm_mfma<1><<<dim3(16, 16, 3), blk, 0, stream>>>(Xh, WT, bq, bk, bv, Qh, Kh, Vt);
    attn_k<<<dim3(1024), dim3(512), 0, stream>>>(Qh, Kh, Vt, pm, iw, comb);
    gemm_mfma<0><<<dim3(16, 16, 1), blk, 0, stream>>>(
        comb, WT + (3u << 20), bo, bo, bo, out, out, out);
}